// Round 11
// baseline (158.697 us; speedup 1.0000x reference)
//
#include <hip/hip_runtime.h>
#include <hip/hip_bf16.h>
#include <math.h>

// Problem constants (B=2, C=256, H=W=64, Co=256, 3x3, stride1, pad1)
#define BB 2
#define CC 256
#define HH 64
#define WW 64
#define COo 256
#define HWs 4096
#define K2 9
#define CK 2304   // C*9

typedef __attribute__((ext_vector_type(4))) float floatx4;
typedef __attribute__((ext_vector_type(8))) short shortx8;   // 8 bf16

// ---- workspace layout (float units) ----
#define O_WBF   221184     // reg_w bf16 [co][k*256+c] = 294912 f  (tap-major)
#define O_WPK   516096     // convA weights [g2][kc8][tap9][nf2][lane][8] = 73728 f
#define O_XT    10027008   // x NHWC bf16 [b][y][x][c] = 1048576 f
#define O_RT    11075584   // residual NHWC bf16 = 1048576 f

__device__ __forceinline__ void gll16(const __hip_bfloat16* g, __hip_bfloat16* l) {
    __builtin_amdgcn_global_load_lds(
        (const __attribute__((address_space(1))) unsigned int*)g,
        (__attribute__((address_space(3))) unsigned int*)l, 16, 0, 0);
}

__device__ __forceinline__ short f2bf(float v) {
    __hip_bfloat16 h = __float2bfloat16(v);
    return *reinterpret_cast<short*>(&h);
}

__device__ __forceinline__ float bf2f(short s) {
    unsigned u = ((unsigned)(unsigned short)s) << 16;
    return __builtin_bit_cast(float, u);
}

// ---------------------------------------------------------------------------
// K0: FUSED prep = transpose (blocks 0..2047) + weight pack (blocks 2048+).
// Wbf tap-major: Wbf[co*2304 + k*256 + c] = reg_w[co][c][k]. (verbatim R17)
// ---------------------------------------------------------------------------
__global__ __launch_bounds__(256) void prep_kernel(
    const float* __restrict__ x,
    const float* __restrict__ residual,
    const float* __restrict__ reg_w,
    const float* __restrict__ off_w,
    const float* __restrict__ mod_w,
    __hip_bfloat16* __restrict__ xT,
    __hip_bfloat16* __restrict__ resT,
    __hip_bfloat16* __restrict__ Wbf,
    __hip_bfloat16* __restrict__ Wpk)
{
    int blk = blockIdx.x;
    int t = threadIdx.x;
    if (blk < 2048) {
        int sel = blk >> 10;             // 0 = x, 1 = residual
        int bk  = blk & 1023;            // ((b*64 + y)*8 + oc)
        int oc = bk & 7;
        int y  = (bk >> 3) & 63;
        int b  = bk >> 9;
        int wo = t & 63;
        int cg = t >> 6;
        int c0 = oc * 32 + cg * 8;
        const float* src = (sel ? residual : x)
                           + ((size_t)(b * CC + c0) * HH + y) * WW + wo;
        shortx8 pk;
#pragma unroll
        for (int j = 0; j < 8; ++j) pk[j] = f2bf(src[(size_t)j * HWs]);
        __hip_bfloat16* dst = sel ? resT : xT;
        *(shortx8*)(dst + ((size_t)b * 4096 + y * 64 + wo) * 256 + c0) = pk;
    } else {
        int idx = (blk - 2048) * 256 + t;
        if (idx < CK * COo) {
            // dst (co, k, c) <- reg_w[co*2304 + c*9 + k]
            int co = idx / CK;
            int r  = idx - co * CK;
            int k  = r >> 8;
            int c  = r & 255;
            Wbf[idx] = __float2bfloat16(reg_w[(size_t)co * CK + c * 9 + k]);
        }
        if (idx < 147456) {
            int g    = idx / 73728;
            int rem  = idx % 73728;
            int kc   = rem / 9216;
            int r2   = rem % 9216;
            int tap  = r2 / 1024;
            int r3   = r2 & 1023;
            int nf   = r3 >> 9;
            int r4   = r3 & 511;
            int lane = r4 >> 3;
            int j    = r4 & 7;
            int c    = kc * 32 + (lane >> 4) * 8 + j;
            int n    = nf * 16 + (lane & 15);
            float v = 0.f;
            if (g == 0) { if (n < 18) v = off_w[((size_t)n * CC + c) * 9 + tap]; }
            else        { if (n < 9)  v = mod_w[((size_t)n * CC + c) * 9 + tap]; }
            Wpk[idx] = __float2bfloat16(v);
        }
    }
}

// ---------------------------------------------------------------------------
// K1 (R21): MEGA kernel = conv prologue + gather + GEMM in ONE launch.
// convA2 is DELETED as a separate kernel: each gemm block needs off/mask for
// exactly its own 32 pixels, so the conv runs as a per-block prologue.
//   - Wave w: g = w>>1 (0: offset conv on resT; 1: modulator conv on xT),
//     ph = w&1 (16-pixel half). Each wave accumulates FULL K serially
//     (tap 0..8 x kc 0..7) = R0's original validated conv order (no split,
//     no reduction). g=1 waves use acc0 only (R20-validated trim).
//   - Results -> LDS s_off[32][18] / s_msk[32][9] (+3.4 KB -> 57.4 KB LDS,
//     still 2 blocks/CU). Meta prologue reads LDS instead of global.
//   - off/mask global buffers and the convA2 launch + inter-kernel
//     serialization disappear. Conv work duplicated across the nt pair
//     (~1-2 us/block, partly hidden under the B0 DMA).
// Main K-loop, barriers, depth-1 gather pipeline, epilogue: verbatim R17
// (validated 130.6). Prologue adds conv -> sync -> meta -> sync, both clean.
// ---------------------------------------------------------------------------
__global__ __launch_bounds__(256) void mega_kernel(
    const __hip_bfloat16* __restrict__ xT,
    const __hip_bfloat16* __restrict__ resT,
    const __hip_bfloat16* __restrict__ Wpk,
    const float* __restrict__ off_b,
    const float* __restrict__ mod_b,
    const __hip_bfloat16* __restrict__ Wbf,
    float* __restrict__ out)
{
    int blk0 = blockIdx.x;
    int blk = ((blk0 & 7) << 6) | (blk0 >> 3);   // XCD chunking, bijective on 512
    int nt = blk & 1;
    int mt = blk >> 1;              // 0..255 (32-pixel tiles)
    int t  = threadIdx.x;
    int lane = t & 63;
    int w    = t >> 6;              // 0..3
    int quad = lane >> 4;
    int ln   = lane & 15;
    int wm = w & 1;                 // M half (16 rows)
    int wn = w >> 1;                // N half (64 cols)

    __shared__ __hip_bfloat16 As[2][32 * 64];    // 8 KB
    __shared__ __hip_bfloat16 Bs[2][128 * 64];   // 32 KB
    __shared__ int   s_mi[32][K2][4];            // 4.5 KB corner indices
    __shared__ float s_mw[32][K2][4];            // 4.5 KB corner weights (x mask)
    __shared__ float s_out[4][16 * 20];          // 5 KB epilogue
    __shared__ float s_off[32][18];              // 2.25 KB conv offsets
    __shared__ float s_msk[32][9];               // 1.125 KB conv modulator
    // total ~57.4 KB -> 2 blocks/CU

    int b = mt >> 7;
    const __hip_bfloat16* xb = xT + (size_t)b * 4096 * 256;

    int lr8 = lane >> 3;            // staging row within 8
    int sub = lane & 7;             // 16B slot
    int chk = sub ^ lr8;            // pre-swizzled global k-chunk

    const __hip_bfloat16* gB = Wbf + (size_t)(nt * 128 + w * 8 + lr8) * CK + chk * 8;
    int lof = w * 512;

    floatx4 acc[4];
#pragma unroll
    for (int nf = 0; nf < 4; ++nf) acc[nf] = (floatx4){0.f, 0.f, 0.f, 0.f};

    // issue B buf0 DMA first (latency hides under the conv prologue)
#pragma unroll
    for (int h = 0; h < 4; ++h)
        gll16(gB + (size_t)(h * 32) * CK, &Bs[0][lof + h * 2048]);

    // ==================== conv prologue (per-block off/mask) ===============
    {
        int cgv = w >> 1;           // 0: offset conv (resT), 1: modulator (xT)
        int cph = w & 1;            // pixel half
        const __hip_bfloat16* csrc = (cgv ? xT : resT) + (size_t)b * 4096 * 256;
        const __hip_bfloat16* cwg  = Wpk + (size_t)cgv * 73728;
        int chwl = (mt & 127) * 32 + cph * 16 + ln;   // this lane's pixel (A-row)
        int cho = chwl >> 6, cwo = chwl & 63;

        floatx4 ca0 = (floatx4){0.f, 0.f, 0.f, 0.f};
        floatx4 ca1 = (floatx4){0.f, 0.f, 0.f, 0.f};

#pragma unroll
        for (int tap = 0; tap < 9; ++tap) {
            int ky = tap / 3, kx = tap % 3;
            int r  = cho + ky - 1;
            int cx = cwo + kx - 1;
            bool v = (r >= 0) && (r < HH) && (cx >= 0) && (cx < WW);
            int hw = v ? (r * WW + cx) : 0;
            const __hip_bfloat16* abase = csrc + (size_t)hw * 256 + quad * 8;
            const __hip_bfloat16* wbase = cwg + (size_t)tap * 1024 + lane * 8;
#pragma unroll
            for (int kc = 0; kc < 8; ++kc) {
                shortx8 af = *(const shortx8*)(abase + kc * 32);
                if (!v) {
                    shortx8 zf = {0,0,0,0,0,0,0,0};
                    af = zf;
                }
                shortx8 b0 = *(const shortx8*)(wbase + (size_t)kc * 9216);
                ca0 = __builtin_amdgcn_mfma_f32_16x16x32_bf16(af, b0, ca0, 0, 0, 0);
                if (cgv == 0) {     // wave-uniform branch
                    shortx8 b1 = *(const shortx8*)(wbase + (size_t)kc * 9216 + 512);
                    ca1 = __builtin_amdgcn_mfma_f32_16x16x32_bf16(af, b1, ca1, 0, 0, 0);
                }
            }
        }

        // conv epilogue -> LDS. C/D: col = ln (=n), row = quad*4+i2 (pixel)
        if (cgv == 0) {
#pragma unroll
            for (int i2 = 0; i2 < 4; ++i2) {
                int p = cph * 16 + quad * 4 + i2;
                s_off[p][ln] = ca0[i2] + off_b[ln];
                if (ln < 2) s_off[p][16 + ln] = ca1[i2] + off_b[16 + ln];
            }
        } else {
#pragma unroll
            for (int i2 = 0; i2 < 4; ++i2) {
                int p = cph * 16 + quad * 4 + i2;
                if (ln < 9) {
                    float z = ca0[i2] + mod_b[ln];
                    s_msk[p][ln] = 2.f / (1.f + __expf(-z));
                }
            }
        }
    }
    __syncthreads();                // conv results visible (B0 DMA also drained)

    // ---- meta prologue: corner idx/weights for 32 pixels x 9 taps (LDS) ----
    for (int u = t; u < 32 * K2; u += 256) {
        int pl_ = u / K2;
        int k  = u - pl_ * K2;
        int hw = (mt & 127) * 32 + pl_;
        int ho = hw >> 6, wo = hw & 63;
        float dy = s_off[pl_][2 * k];
        float dx = s_off[pl_][2 * k + 1];
        float m  = s_msk[pl_][k];
        float py = (float)(ho - 1 + k / 3) + dy;
        float px = (float)(wo - 1 + k % 3) + dx;
        float y0f = floorf(py), x0f = floorf(px);
        float wy1 = py - y0f, wx1 = px - x0f;
        float wy0 = 1.f - wy1, wx0 = 1.f - wx1;
        int y0 = (int)y0f, x0 = (int)x0f;
#pragma unroll
        for (int j = 0; j < 4; ++j) {
            int yy = y0 + (j >> 1);
            int xx = x0 + (j & 1);
            float wj = ((j == 0) ? wy0 * wx0 :
                        (j == 1) ? wy0 * wx1 :
                        (j == 2) ? wy1 * wx0 : wy1 * wx1) * m;
            bool valid = (yy >= 0) && (yy < HH) && (xx >= 0) && (xx < WW);
            s_mi[pl_][k][j] = valid ? (yy * WW + xx) : 0;
            s_mw[pl_][k][j] = valid ? wj : 0.f;
        }
    }

    int pl  = t >> 3;               // gather: this thread's pixel (0..31)
    int ch8 = t & 7;                // gather: 8-channel group within 64
    int aslot = pl * 64 + ((ch8 ^ (pl & 7)) * 8);   // swizzled As column

    // per-tap meta (for the step currently being LOADED)
    int   mi0, mi1, mi2, mi3;
    float mw0, mw1, mw2, mw3;
    auto meta_load = [&](int k) {
        mi0 = s_mi[pl][k][0]; mi1 = s_mi[pl][k][1];
        mi2 = s_mi[pl][k][2]; mi3 = s_mi[pl][k][3];
        mw0 = s_mw[pl][k][0]; mw1 = s_mw[pl][k][1];
        mw2 = s_mw[pl][k][2]; mw3 = s_mw[pl][k][3];
    };

    // in-flight gather state: loaded corners + their weights (snapshot)
    shortx8 gc0, gc1, gc2, gc3;
    float   gw0, gw1, gw2, gw3;
    auto gather_load = [&](int cb) {
        const __hip_bfloat16* xr = xb + cb * 64 + ch8 * 8;
        gc0 = *(const shortx8*)(xr + (size_t)mi0 * 256);
        gc1 = *(const shortx8*)(xr + (size_t)mi1 * 256);
        gc2 = *(const shortx8*)(xr + (size_t)mi2 * 256);
        gc3 = *(const shortx8*)(xr + (size_t)mi3 * 256);
        gw0 = mw0; gw1 = mw1; gw2 = mw2; gw3 = mw3;
    };
    auto gather_store = [&](int buf) {
        shortx8 o;
#pragma unroll
        for (int j = 0; j < 8; ++j)
            o[j] = f2bf(gw0 * bf2f(gc0[j]) + gw1 * bf2f(gc1[j])
                      + gw2 * bf2f(gc2[j]) + gw3 * bf2f(gc3[j]));
        *(shortx8*)&As[buf][aslot] = o;
    };

    __syncthreads();                // meta visible
    meta_load(0);
    gather_load(0);                 // corners for step 0
    gather_store(0);                // exposed once (prologue only)
    gather_load(1);                 // corners for step 1 (cb=1, tap 0)

    int swz = ln & 7;               // read-slot XOR key

    for (int kt = 0; kt < 36; ++kt) {
        int cur = kt & 1;
        int nxt = cur ^ 1;
        __syncthreads();            // buf[cur] staged; ALSO drains gc loads
        if (kt + 1 < 36) {
            int ko = (kt + 1) * 64;
#pragma unroll
            for (int h = 0; h < 4; ++h)
                gll16(gB + (size_t)(h * 32) * CK + ko, &Bs[nxt][lof + h * 2048]);
        }
#pragma unroll
        for (int kh = 0; kh < 2; ++kh) {
            int slot = ((kh * 4 + quad) ^ swz) * 8;
            shortx8 af = *(const shortx8*)
                &As[cur][(wm * 16 + ln) * 64 + slot];
            shortx8 bf[4];
#pragma unroll
            for (int nf = 0; nf < 4; ++nf)
                bf[nf] = *(const shortx8*)
                    &Bs[cur][(wn * 64 + nf * 16 + ln) * 64 + slot];
#pragma unroll
            for (int nf = 0; nf < 4; ++nf)
                acc[nf] = __builtin_amdgcn_mfma_f32_16x16x32_bf16(
                    af, bf[nf], acc[nf], 0, 0, 0);
        }
        if (kt + 1 < 36) gather_store(nxt);   // gc drained -> zero-wait consume
        if (kt + 2 < 36) {                    // issue loads for step kt+2
            int k2 = kt + 2;
            if ((k2 & 3) == 0) meta_load(k2 >> 2);
            gather_load(k2 & 3);
        }
    }

    // epilogue (verbatim R13/R14/R17): per-wave LDS transpose
    int bb = mt >> 7;
    int hw0 = (mt & 127) * 32 + wm * 16;
    float* sw = &s_out[w][0];
    int co_l = lane >> 2;
    int seg  = lane & 3;
#pragma unroll
    for (int nf = 0; nf < 4; ++nf) {
        *(floatx4*)&sw[ln * 20 + quad * 4] = acc[nf];
        floatx4 v0 = *(const floatx4*)&sw[co_l * 20 + seg * 4];
        int co = nt * 128 + wn * 64 + nf * 16 + co_l;
        float* orow = out + ((size_t)(bb * COo + co) << 12) + hw0;
        *(floatx4*)&orow[seg * 4] = v0;
    }
}

// ---------------------------------------------------------------------------
extern "C" void kernel_launch(void* const* d_in, const int* in_sizes, int n_in,
                              void* d_out, int out_size, void* d_ws, size_t ws_size,
                              hipStream_t stream)
{
    const float* x     = (const float*)d_in[0];
    const float* resid = (const float*)d_in[1];
    const float* off_w = (const float*)d_in[2];
    const float* off_b = (const float*)d_in[3];
    const float* mod_w = (const float*)d_in[4];
    const float* mod_b = (const float*)d_in[5];
    const float* reg_w = (const float*)d_in[6];
    float* out = (float*)d_out;

    float* ws = (float*)d_ws;
    __hip_bfloat16* Wbf  = (__hip_bfloat16*)(ws + O_WBF);
    __hip_bfloat16* Wpk  = (__hip_bfloat16*)(ws + O_WPK);
    __hip_bfloat16* xT   = (__hip_bfloat16*)(ws + O_XT);
    __hip_bfloat16* resT = (__hip_bfloat16*)(ws + O_RT);

    // fused transpose (2048 blocks) + weight pack (2304 blocks)
    prep_kernel<<<2048 + (CK * COo + 255) / 256, 256, 0, stream>>>(
        x, resid, reg_w, off_w, mod_w, xT, resT, Wbf, Wpk);

    mega_kernel<<<512, 256, 0, stream>>>(xT, resT, Wpk, off_b, mod_b, Wbf, out);
}

// Round 12
// 129.248 us; speedup vs baseline: 1.2278x; 1.2278x over previous
//
#include <hip/hip_runtime.h>
#include <hip/hip_bf16.h>
#include <math.h>

// Problem constants (B=2, C=256, H=W=64, Co=256, 3x3, stride1, pad1)
#define BB 2
#define CC 256
#define HH 64
#define WW 64
#define COo 256
#define HWs 4096
#define K2 9
#define CK 2304   // C*9

typedef __attribute__((ext_vector_type(4))) float floatx4;
typedef __attribute__((ext_vector_type(8))) short shortx8;   // 8 bf16

// ---- workspace layout (float units) ----
#define O_OFF   0          // final offset  B*18*4096 = 147456 f
#define O_MASK  147456     // final modulator B*9*4096 = 73728 f
#define O_WBF   221184     // reg_w bf16 [co][k*256+c] = 294912 f  (tap-major)
#define O_WPK   516096     // convA weights [g2][kc8][tap9][nf2][lane][8] = 73728 f
#define O_XT    10027008   // x NHWC bf16 [b][y][x][c] = 1048576 f
#define O_RT    11075584   // residual NHWC bf16 = 1048576 f

__device__ __forceinline__ void gll16(const __hip_bfloat16* g, __hip_bfloat16* l) {
    __builtin_amdgcn_global_load_lds(
        (const __attribute__((address_space(1))) unsigned int*)g,
        (__attribute__((address_space(3))) unsigned int*)l, 16, 0, 0);
}

__device__ __forceinline__ short f2bf(float v) {
    __hip_bfloat16 h = __float2bfloat16(v);
    return *reinterpret_cast<short*>(&h);
}

__device__ __forceinline__ float bf2f(short s) {
    unsigned u = ((unsigned)(unsigned short)s) << 16;
    return __builtin_bit_cast(float, u);
}

// ---------------------------------------------------------------------------
// K0: FUSED prep = transpose (blocks 0..2047) + weight pack (blocks 2048+).
// Wbf tap-major: Wbf[co*2304 + k*256 + c] = reg_w[co][c][k]. (verbatim R17)
// ---------------------------------------------------------------------------
__global__ __launch_bounds__(256) void prep_kernel(
    const float* __restrict__ x,
    const float* __restrict__ residual,
    const float* __restrict__ reg_w,
    const float* __restrict__ off_w,
    const float* __restrict__ mod_w,
    __hip_bfloat16* __restrict__ xT,
    __hip_bfloat16* __restrict__ resT,
    __hip_bfloat16* __restrict__ Wbf,
    __hip_bfloat16* __restrict__ Wpk)
{
    int blk = blockIdx.x;
    int t = threadIdx.x;
    if (blk < 2048) {
        int sel = blk >> 10;             // 0 = x, 1 = residual
        int bk  = blk & 1023;            // ((b*64 + y)*8 + oc)
        int oc = bk & 7;
        int y  = (bk >> 3) & 63;
        int b  = bk >> 9;
        int wo = t & 63;
        int cg = t >> 6;
        int c0 = oc * 32 + cg * 8;
        const float* src = (sel ? residual : x)
                           + ((size_t)(b * CC + c0) * HH + y) * WW + wo;
        shortx8 pk;
#pragma unroll
        for (int j = 0; j < 8; ++j) pk[j] = f2bf(src[(size_t)j * HWs]);
        __hip_bfloat16* dst = sel ? resT : xT;
        *(shortx8*)(dst + ((size_t)b * 4096 + y * 64 + wo) * 256 + c0) = pk;
    } else {
        int idx = (blk - 2048) * 256 + t;
        if (idx < CK * COo) {
            // dst (co, k, c) <- reg_w[co*2304 + c*9 + k]
            int co = idx / CK;
            int r  = idx - co * CK;
            int k  = r >> 8;
            int c  = r & 255;
            Wbf[idx] = __float2bfloat16(reg_w[(size_t)co * CK + c * 9 + k]);
        }
        if (idx < 147456) {
            int g    = idx / 73728;
            int rem  = idx % 73728;
            int kc   = rem / 9216;
            int r2   = rem % 9216;
            int tap  = r2 / 1024;
            int r3   = r2 & 1023;
            int nf   = r3 >> 9;
            int r4   = r3 & 511;
            int lane = r4 >> 3;
            int j    = r4 & 7;
            int c    = kc * 32 + (lane >> 4) * 8 + j;
            int n    = nf * 16 + (lane & 15);
            float v = 0.f;
            if (g == 0) { if (n < 18) v = off_w[((size_t)n * CC + c) * 9 + tap]; }
            else        { if (n < 9)  v = mod_w[((size_t)n * CC + c) * 9 + tap]; }
            Wpk[idx] = __float2bfloat16(v);
        }
    }
}

// ---------------------------------------------------------------------------
// K1: DIRECT offset+modulator conv. (verbatim R20: R17 structure + g=1 trim,
// validated 131.2. R21's in-block fusion REVERTED: serializing full-K conv
// into each gemm block at 2 blk/CU cost +27us — occupancy lesson in reverse.)
// ---------------------------------------------------------------------------
__global__ __launch_bounds__(512) void convA2_kernel(
    const __hip_bfloat16* __restrict__ xT,
    const __hip_bfloat16* __restrict__ resT,
    const __hip_bfloat16* __restrict__ Wpk,
    const float* __restrict__ off_b,
    const float* __restrict__ mod_b,
    float* __restrict__ off_out,
    float* __restrict__ mask_out)
{
    int blk = blockIdx.x;
    int tile = blk & 127;
    int g = (blk >> 7) & 1;
    int b = blk >> 8;
    int t = threadIdx.x;
    int lane = t & 63;
    int w = t >> 6;                  // 0..7
    int ph = w & 1;                  // pixel half (16 pixels)
    int ks = w >> 1;                 // K quarter (kc pair)
    int ln = lane & 15;
    int quad = lane >> 4;

    const __hip_bfloat16* src = (g ? xT : resT) + (size_t)b * 4096 * 256;
    const __hip_bfloat16* wg  = Wpk + (size_t)g * 73728 + (size_t)ks * 2 * 9216;

    int pix = tile * 32 + ph * 16 + ln;   // this lane's A-row (pixel)
    int ho = pix >> 6, wo = pix & 63;

    floatx4 acc0 = (floatx4){0.f, 0.f, 0.f, 0.f};
    floatx4 acc1 = (floatx4){0.f, 0.f, 0.f, 0.f};

    if (g == 0) {
#pragma unroll
        for (int tap = 0; tap < 9; ++tap) {
            int ky = tap / 3, kx = tap % 3;
            int r  = ho + ky - 1;
            int cx = wo + kx - 1;
            bool v = (r >= 0) && (r < HH) && (cx >= 0) && (cx < WW);
            int hw = v ? (r * WW + cx) : 0;
            const __hip_bfloat16* abase = src + (size_t)hw * 256 + quad * 8 + ks * 64;
            const __hip_bfloat16* wbase = wg + (size_t)tap * 1024 + lane * 8;
#pragma unroll
            for (int kc = 0; kc < 2; ++kc) {
                shortx8 af = *(const shortx8*)(abase + kc * 32);
                if (!v) {
                    shortx8 zf = {0,0,0,0,0,0,0,0};
                    af = zf;
                }
                shortx8 b0 = *(const shortx8*)(wbase + (size_t)kc * 9216);
                shortx8 b1 = *(const shortx8*)(wbase + (size_t)kc * 9216 + 512);
                acc0 = __builtin_amdgcn_mfma_f32_16x16x32_bf16(af, b0, acc0, 0, 0, 0);
                acc1 = __builtin_amdgcn_mfma_f32_16x16x32_bf16(af, b1, acc1, 0, 0, 0);
            }
        }
    } else {
#pragma unroll
        for (int tap = 0; tap < 9; ++tap) {
            int ky = tap / 3, kx = tap % 3;
            int r  = ho + ky - 1;
            int cx = wo + kx - 1;
            bool v = (r >= 0) && (r < HH) && (cx >= 0) && (cx < WW);
            int hw = v ? (r * WW + cx) : 0;
            const __hip_bfloat16* abase = src + (size_t)hw * 256 + quad * 8 + ks * 64;
            const __hip_bfloat16* wbase = wg + (size_t)tap * 1024 + lane * 8;
#pragma unroll
            for (int kc = 0; kc < 2; ++kc) {
                shortx8 af = *(const shortx8*)(abase + kc * 32);
                if (!v) {
                    shortx8 zf = {0,0,0,0,0,0,0,0};
                    af = zf;
                }
                shortx8 b0 = *(const shortx8*)(wbase + (size_t)kc * 9216);
                acc0 = __builtin_amdgcn_mfma_f32_16x16x32_bf16(af, b0, acc0, 0, 0, 0);
            }
        }
    }

    __shared__ float s_red[8][64][8];    // 16 KB
    *(floatx4*)&s_red[w][lane][0] = acc0;
    *(floatx4*)&s_red[w][lane][4] = acc1;
    __syncthreads();
    if (w < 2) {                         // w == ph, ks == 0
#pragma unroll
        for (int j = 0; j < 4; ++j) {
            acc0[j] = s_red[w][lane][j]     + s_red[w + 2][lane][j]
                    + s_red[w + 4][lane][j] + s_red[w + 6][lane][j];
            acc1[j] = s_red[w][lane][4 + j]     + s_red[w + 2][lane][4 + j]
                    + s_red[w + 4][lane][4 + j] + s_red[w + 6][lane][4 + j];
        }

#pragma unroll
        for (int nf = 0; nf < 2; ++nf) {
            floatx4 a = nf ? acc1 : acc0;
            int n = nf * 16 + ln;
#pragma unroll
            for (int i2 = 0; i2 < 4; ++i2) {
                int p = tile * 32 + w * 16 + quad * 4 + i2;
                if (g == 0) {
                    if (n < 18)
                        off_out[((size_t)b * 18 + n) * HWs + p] = a[i2] + off_b[n];
                } else {
                    if (n < 9) {
                        float z = a[i2] + mod_b[n];
                        mask_out[((size_t)b * 9 + n) * HWs + p] =
                            2.f / (1.f + __expf(-z));
                    }
                }
            }
        }
    }
}

// ---------------------------------------------------------------------------
// K2 (R22): FUSED gather+GEMM, BN=256 @ 16 waves. R15 (BN=256, 8 waves =
// 2 wv/SIMD) measured 44us with Occ 19% / MfmaUtil 7.5% — everything idle.
// R22 keeps R15's dedup benefits (gather ONCE per mt, B read once; grid 256
// = exactly 1 block/CU, 1 round) but at 1024 threads = 16 waves = 4 wv/SIMD
// so co-resident waves cover the per-step barrier drain.
//   - wave w: wm = w&1 (16-row half), wN = w>>1 (32-col group of 8); acc[2].
//   - per-output K-sequence (kt 0..35, kh 0..1) IDENTICAL to R17/R20.
//   - skeleton verbatim-R17: one __syncthreads/step, dbuf B-DMA (2 gll16/
//     wave/step), XOR chunk/read swizzles, depth-1 cross-step gather
//     pipeline (threads 0..255, wave-uniform), R13 epilogue.
// LDS: As 8K + Bs 64K + meta 9K + s_out 20K = ~101 KB -> 1 block/CU.
// ---------------------------------------------------------------------------
__global__ __launch_bounds__(1024) void gemm_fused_kernel(
    const __hip_bfloat16* __restrict__ xT,
    const float* __restrict__ off,
    const float* __restrict__ mask,
    const __hip_bfloat16* __restrict__ Wbf,
    float* __restrict__ out)
{
    int blk0 = blockIdx.x;
    int mt = ((blk0 & 7) << 5) | (blk0 >> 3);   // XCD chunking, bijective on 256
    int t  = threadIdx.x;
    int lane = t & 63;
    int w    = t >> 6;              // 0..15
    int quad = lane >> 4;
    int ln   = lane & 15;
    int wm = w & 1;                 // M half (16 rows)
    int wN = w >> 1;                // 32-col group (0..7)

    __shared__ __hip_bfloat16 As[2][32 * 64];    // 8 KB
    __shared__ __hip_bfloat16 Bs[2][256 * 64];   // 64 KB
    __shared__ int   s_mi[32][K2][4];            // 4.5 KB corner indices
    __shared__ float s_mw[32][K2][4];            // 4.5 KB corner weights (x mask)
    __shared__ float s_out[16][16 * 20];         // 20 KB epilogue

    int b = mt >> 7;
    const __hip_bfloat16* xb = xT + (size_t)b * 4096 * 256;

    int lr8 = lane >> 3;            // staging row within 8
    int sub = lane & 7;             // 16B slot
    int chk = sub ^ lr8;            // pre-swizzled global k-chunk

    // wave w stages B rows {w*16 + h*8 + lr8 : h=0,1} (2 gll16/step)
    const __hip_bfloat16* gB = Wbf + (size_t)(w * 16 + lr8) * CK + chk * 8;

    floatx4 acc[2];
#pragma unroll
    for (int nf = 0; nf < 2; ++nf) acc[nf] = (floatx4){0.f, 0.f, 0.f, 0.f};

    // issue B buf0 DMA first (latency overlaps meta compute)
#pragma unroll
    for (int h = 0; h < 2; ++h)
        gll16(gB + (size_t)(h * 8) * CK, &Bs[0][w * 1024 + h * 512]);

    // ---- meta prologue: corner idx/weights for 32 pixels x 9 taps ----
    for (int u = t; u < 32 * K2; u += 1024) {
        int pl_ = u / K2;
        int k  = u - pl_ * K2;
        int hw = (mt & 127) * 32 + pl_;
        int ho = hw >> 6, wo = hw & 63;
        float dy = off [(((size_t)b * 18 + 2 * k    ) << 12) + hw];
        float dx = off [(((size_t)b * 18 + 2 * k + 1) << 12) + hw];
        float m  = mask[(((size_t)b * 9  + k        ) << 12) + hw];
        float py = (float)(ho - 1 + k / 3) + dy;
        float px = (float)(wo - 1 + k % 3) + dx;
        float y0f = floorf(py), x0f = floorf(px);
        float wy1 = py - y0f, wx1 = px - x0f;
        float wy0 = 1.f - wy1, wx0 = 1.f - wx1;
        int y0 = (int)y0f, x0 = (int)x0f;
#pragma unroll
        for (int j = 0; j < 4; ++j) {
            int yy = y0 + (j >> 1);
            int xx = x0 + (j & 1);
            float wj = ((j == 0) ? wy0 * wx0 :
                        (j == 1) ? wy0 * wx1 :
                        (j == 2) ? wy1 * wx0 : wy1 * wx1) * m;
            bool valid = (yy >= 0) && (yy < HH) && (xx >= 0) && (xx < WW);
            s_mi[pl_][k][j] = valid ? (yy * WW + xx) : 0;
            s_mw[pl_][k][j] = valid ? wj : 0.f;
        }
    }

    int pl  = (t >> 3) & 31;        // gather pixel (0..31), threads 0..255
    int ch8 = t & 7;                // 8-channel group within 64
    bool gth = (t < 256);           // gather workers = waves 0..3 (uniform)
    int aslot = pl * 64 + ((ch8 ^ (pl & 7)) * 8);   // swizzled As column

    // per-tap meta (for the step currently being LOADED)
    int   mi0, mi1, mi2, mi3;
    float mw0, mw1, mw2, mw3;
    auto meta_load = [&](int k) {
        mi0 = s_mi[pl][k][0]; mi1 = s_mi[pl][k][1];
        mi2 = s_mi[pl][k][2]; mi3 = s_mi[pl][k][3];
        mw0 = s_mw[pl][k][0]; mw1 = s_mw[pl][k][1];
        mw2 = s_mw[pl][k][2]; mw3 = s_mw[pl][k][3];
    };

    // in-flight gather state: loaded corners + their weights (snapshot)
    shortx8 gc0, gc1, gc2, gc3;
    float   gw0, gw1, gw2, gw3;
    auto gather_load = [&](int cb) {
        const __hip_bfloat16* xr = xb + cb * 64 + ch8 * 8;
        gc0 = *(const shortx8*)(xr + (size_t)mi0 * 256);
        gc1 = *(const shortx8*)(xr + (size_t)mi1 * 256);
        gc2 = *(const shortx8*)(xr + (size_t)mi2 * 256);
        gc3 = *(const shortx8*)(xr + (size_t)mi3 * 256);
        gw0 = mw0; gw1 = mw1; gw2 = mw2; gw3 = mw3;
    };
    auto gather_store = [&](int buf) {
        shortx8 o;
#pragma unroll
        for (int j = 0; j < 8; ++j)
            o[j] = f2bf(gw0 * bf2f(gc0[j]) + gw1 * bf2f(gc1[j])
                      + gw2 * bf2f(gc2[j]) + gw3 * bf2f(gc3[j]));
        *(shortx8*)&As[buf][aslot] = o;
    };

    __syncthreads();                // meta visible (also drains B0 DMA)
    if (gth) {
        meta_load(0);
        gather_load(0);             // corners for step 0
        gather_store(0);            // exposed once (prologue only)
        gather_load(1);             // corners for step 1 (cb=1, tap 0)
    }

    int swz = ln & 7;               // read-slot XOR key

    for (int kt = 0; kt < 36; ++kt) {
        int cur = kt & 1;
        int nxt = cur ^ 1;
        __syncthreads();            // buf[cur] staged; ALSO drains gc loads
        if (kt + 1 < 36) {
            int ko = (kt + 1) * 64;
#pragma unroll
            for (int h = 0; h < 2; ++h)
                gll16(gB + (size_t)(h * 8) * CK + ko, &Bs[nxt][w * 1024 + h * 512]);
        }
#pragma unroll
        for (int kh = 0; kh < 2; ++kh) {
            int slot = ((kh * 4 + quad) ^ swz) * 8;
            shortx8 af = *(const shortx8*)
                &As[cur][(wm * 16 + ln) * 64 + slot];
            shortx8 bf[2];
#pragma unroll
            for (int nf = 0; nf < 2; ++nf)
                bf[nf] = *(const shortx8*)
                    &Bs[cur][(wN * 32 + nf * 16 + ln) * 64 + slot];
#pragma unroll
            for (int nf = 0; nf < 2; ++nf)
                acc[nf] = __builtin_amdgcn_mfma_f32_16x16x32_bf16(
                    af, bf[nf], acc[nf], 0, 0, 0);
        }
        if (gth && kt + 1 < 36) gather_store(nxt);   // drained -> zero-wait
        if (gth && kt + 2 < 36) {                    // issue loads for kt+2
            int k2 = kt + 2;
            if ((k2 & 3) == 0) meta_load(k2 >> 2);
            gather_load(k2 & 3);
        }
    }

    // epilogue (R13-validated pattern): per-wave LDS transpose
    int bb = mt >> 7;
    int hw0 = (mt & 127) * 32 + wm * 16;
    float* sw = &s_out[w][0];
    int co_l = lane >> 2;
    int seg  = lane & 3;
#pragma unroll
    for (int nf = 0; nf < 2; ++nf) {
        *(floatx4*)&sw[ln * 20 + quad * 4] = acc[nf];
        floatx4 v0 = *(const floatx4*)&sw[co_l * 20 + seg * 4];
        int co = wN * 32 + nf * 16 + co_l;
        float* orow = out + ((size_t)(bb * COo + co) << 12) + hw0;
        *(floatx4*)&orow[seg * 4] = v0;
    }
}

// ---------------------------------------------------------------------------
extern "C" void kernel_launch(void* const* d_in, const int* in_sizes, int n_in,
                              void* d_out, int out_size, void* d_ws, size_t ws_size,
                              hipStream_t stream)
{
    const float* x     = (const float*)d_in[0];
    const float* resid = (const float*)d_in[1];
    const float* off_w = (const float*)d_in[2];
    const float* off_b = (const float*)d_in[3];
    const float* mod_w = (const float*)d_in[4];
    const float* mod_b = (const float*)d_in[5];
    const float* reg_w = (const float*)d_in[6];
    float* out = (float*)d_out;

    float* ws = (float*)d_ws;
    float* off_buf   = ws + O_OFF;
    float* mask_buf  = ws + O_MASK;
    __hip_bfloat16* Wbf  = (__hip_bfloat16*)(ws + O_WBF);
    __hip_bfloat16* Wpk  = (__hip_bfloat16*)(ws + O_WPK);
    __hip_bfloat16* xT   = (__hip_bfloat16*)(ws + O_XT);
    __hip_bfloat16* resT = (__hip_bfloat16*)(ws + O_RT);

    // fused transpose (2048 blocks) + weight pack (2304 blocks)
    prep_kernel<<<2048 + (CK * COo + 255) / 256, 256, 0, stream>>>(
        x, resid, reg_w, off_w, mod_w, xT, resT, Wbf, Wpk);

    convA2_kernel<<<512, 512, 0, stream>>>(xT, resT, Wpk, off_b, mod_b,
                                           off_buf, mask_buf);

    gemm_fused_kernel<<<256, 1024, 0, stream>>>(xT, off_buf, mask_buf, Wbf, out);
}

// Round 13
// 127.196 us; speedup vs baseline: 1.2477x; 1.0161x over previous
//
#include <hip/hip_runtime.h>
#include <hip/hip_bf16.h>
#include <math.h>

// Problem constants (B=2, C=256, H=W=64, Co=256, 3x3, stride1, pad1)
#define BB 2
#define CC 256
#define HH 64
#define WW 64
#define COo 256
#define HWs 4096
#define K2 9
#define CK 2304   // C*9

typedef __attribute__((ext_vector_type(4))) float floatx4;
typedef __attribute__((ext_vector_type(8))) short shortx8;   // 8 bf16

// ---- workspace layout (float units) ----
#define O_WBF   221184     // reg_w bf16 [co][k*256+c] = 294912 f  (tap-major)
#define O_WPK   516096     // convA weights [g2][kc8][tap9][nf2][lane][8] = 73728 f
#define O_XT    10027008   // x NHWC bf16 [b][y][x][c] = 1048576 f
#define O_RT    11075584   // residual NHWC bf16 = 1048576 f

__device__ __forceinline__ void gll16(const __hip_bfloat16* g, __hip_bfloat16* l) {
    __builtin_amdgcn_global_load_lds(
        (const __attribute__((address_space(1))) unsigned int*)g,
        (__attribute__((address_space(3))) unsigned int*)l, 16, 0, 0);
}

__device__ __forceinline__ short f2bf(float v) {
    __hip_bfloat16 h = __float2bfloat16(v);
    return *reinterpret_cast<short*>(&h);
}

__device__ __forceinline__ float bf2f(short s) {
    unsigned u = ((unsigned)(unsigned short)s) << 16;
    return __builtin_bit_cast(float, u);
}

// ---------------------------------------------------------------------------
// K0: FUSED prep = transpose (blocks 0..2047) + weight pack (blocks 2048+).
// Wbf tap-major: Wbf[co*2304 + k*256 + c] = reg_w[co][c][k]. (verbatim R17)
// ---------------------------------------------------------------------------
__global__ __launch_bounds__(256) void prep_kernel(
    const float* __restrict__ x,
    const float* __restrict__ residual,
    const float* __restrict__ reg_w,
    const float* __restrict__ off_w,
    const float* __restrict__ mod_w,
    __hip_bfloat16* __restrict__ xT,
    __hip_bfloat16* __restrict__ resT,
    __hip_bfloat16* __restrict__ Wbf,
    __hip_bfloat16* __restrict__ Wpk)
{
    int blk = blockIdx.x;
    int t = threadIdx.x;
    if (blk < 2048) {
        int sel = blk >> 10;             // 0 = x, 1 = residual
        int bk  = blk & 1023;            // ((b*64 + y)*8 + oc)
        int oc = bk & 7;
        int y  = (bk >> 3) & 63;
        int b  = bk >> 9;
        int wo = t & 63;
        int cg = t >> 6;
        int c0 = oc * 32 + cg * 8;
        const float* src = (sel ? residual : x)
                           + ((size_t)(b * CC + c0) * HH + y) * WW + wo;
        shortx8 pk;
#pragma unroll
        for (int j = 0; j < 8; ++j) pk[j] = f2bf(src[(size_t)j * HWs]);
        __hip_bfloat16* dst = sel ? resT : xT;
        *(shortx8*)(dst + ((size_t)b * 4096 + y * 64 + wo) * 256 + c0) = pk;
    } else {
        int idx = (blk - 2048) * 256 + t;
        if (idx < CK * COo) {
            // dst (co, k, c) <- reg_w[co*2304 + c*9 + k]
            int co = idx / CK;
            int r  = idx - co * CK;
            int k  = r >> 8;
            int c  = r & 255;
            Wbf[idx] = __float2bfloat16(reg_w[(size_t)co * CK + c * 9 + k]);
        }
        if (idx < 147456) {
            int g    = idx / 73728;
            int rem  = idx % 73728;
            int kc   = rem / 9216;
            int r2   = rem % 9216;
            int tap  = r2 / 1024;
            int r3   = r2 & 1023;
            int nf   = r3 >> 9;
            int r4   = r3 & 511;
            int lane = r4 >> 3;
            int j    = r4 & 7;
            int c    = kc * 32 + (lane >> 4) * 8 + j;
            int n    = nf * 16 + (lane & 15);
            float v = 0.f;
            if (g == 0) { if (n < 18) v = off_w[((size_t)n * CC + c) * 9 + tap]; }
            else        { if (n < 9)  v = mod_w[((size_t)n * CC + c) * 9 + tap]; }
            Wpk[idx] = __float2bfloat16(v);
        }
    }
}

// ---------------------------------------------------------------------------
// K1 (R23): MEGA = conv phase + gather + GEMM, one launch. R21's fusion
// failed because conv ran serial-K at 4 waves/block, duplicated x2 (nt
// pair). R22's BN=256 geometry fixes both: ONE block per mt and 16 waves,
// so the conv uses the R11-VALIDATED 16-way split (g = w>>3, wr = w&7:
// ph = wr&1, ks = wr>>1 -> 18 iters/wave) at the SAME aggregate occupancy
// as the standalone convA2 (4096 waves = 4/SIMD). Saves: convA2 launch +
// gap, off/mask HBM round-trip.
// Composition (main loop untouched): B0 DMA -> conv (partials -> Bs[1]
// reused as 32 KB s_red scratch; first loop write to Bs[1] is kt=0's
// prefetch, >=2 barriers after the reduce reads) -> sync -> R11 reduce
// (waves wr<2 per g) + bias/sigmoid -> s_off/s_msk LDS -> sync -> meta
// (reads LDS) -> sync -> gather prologue -> verbatim R22 loop.
// LDS: As 8K + Bs 64K + meta 9K + s_out 20K + s_off/s_msk 3.4K ~= 104 KB.
// ---------------------------------------------------------------------------
__global__ __launch_bounds__(1024) void mega_kernel(
    const __hip_bfloat16* __restrict__ xT,
    const __hip_bfloat16* __restrict__ resT,
    const __hip_bfloat16* __restrict__ Wpk,
    const float* __restrict__ off_b,
    const float* __restrict__ mod_b,
    const __hip_bfloat16* __restrict__ Wbf,
    float* __restrict__ out)
{
    int blk0 = blockIdx.x;
    int mt = ((blk0 & 7) << 5) | (blk0 >> 3);   // XCD chunking, bijective on 256
    int t  = threadIdx.x;
    int lane = t & 63;
    int w    = t >> 6;              // 0..15
    int quad = lane >> 4;
    int ln   = lane & 15;
    int wm = w & 1;                 // M half (16 rows)  [gemm]
    int wN = w >> 1;                // 32-col group (0..7) [gemm]

    __shared__ __hip_bfloat16 As[2][32 * 64];    // 8 KB
    __shared__ __hip_bfloat16 Bs[2][256 * 64];   // 64 KB (Bs[1] doubles as s_red)
    __shared__ int   s_mi[32][K2][4];            // 4.5 KB corner indices
    __shared__ float s_mw[32][K2][4];            // 4.5 KB corner weights (x mask)
    __shared__ float s_out[16][16 * 20];         // 20 KB epilogue
    __shared__ float s_off[32][18];              // 2.25 KB conv offsets
    __shared__ float s_msk[32][9];               // 1.125 KB conv modulator

    int b = mt >> 7;
    const __hip_bfloat16* xb = xT + (size_t)b * 4096 * 256;

    int lr8 = lane >> 3;            // staging row within 8
    int sub = lane & 7;             // 16B slot
    int chk = sub ^ lr8;            // pre-swizzled global k-chunk

    // wave w stages B rows {w*16 + h*8 + lr8 : h=0,1} (2 gll16/step)
    const __hip_bfloat16* gB = Wbf + (size_t)(w * 16 + lr8) * CK + chk * 8;

    floatx4 acc[2];
#pragma unroll
    for (int nf = 0; nf < 2; ++nf) acc[nf] = (floatx4){0.f, 0.f, 0.f, 0.f};

    // issue B buf0 DMA first (-> Bs[0]; latency hides under the conv phase)
#pragma unroll
    for (int h = 0; h < 2; ++h)
        gll16(gB + (size_t)(h * 8) * CK, &Bs[0][w * 1024 + h * 512]);

    // ==================== conv phase (R11-validated 16-way split) ==========
    {
        int cg  = w >> 3;           // 0: offset conv (resT), 1: modulator (xT)
        int wr  = w & 7;
        int cph = wr & 1;           // pixel half
        int cks = wr >> 1;          // K quarter
        const __hip_bfloat16* csrc = (cg ? xT : resT) + (size_t)b * 4096 * 256;
        const __hip_bfloat16* cwg  = Wpk + (size_t)cg * 73728
                                         + (size_t)cks * 2 * 9216;
        int cpix = (mt & 127) * 32 + cph * 16 + ln;
        int cho = cpix >> 6, cwo = cpix & 63;

        floatx4 ca0 = (floatx4){0.f, 0.f, 0.f, 0.f};
        floatx4 ca1 = (floatx4){0.f, 0.f, 0.f, 0.f};

        if (cg == 0) {
#pragma unroll
            for (int tap = 0; tap < 9; ++tap) {
                int ky = tap / 3, kx = tap % 3;
                int r  = cho + ky - 1;
                int cx = cwo + kx - 1;
                bool v = (r >= 0) && (r < HH) && (cx >= 0) && (cx < WW);
                int hw = v ? (r * WW + cx) : 0;
                const __hip_bfloat16* abase = csrc + (size_t)hw * 256
                                              + quad * 8 + cks * 64;
                const __hip_bfloat16* wbase = cwg + (size_t)tap * 1024 + lane * 8;
#pragma unroll
                for (int kc = 0; kc < 2; ++kc) {
                    shortx8 af = *(const shortx8*)(abase + kc * 32);
                    if (!v) {
                        shortx8 zf = {0,0,0,0,0,0,0,0};
                        af = zf;
                    }
                    shortx8 b0 = *(const shortx8*)(wbase + (size_t)kc * 9216);
                    shortx8 b1 = *(const shortx8*)(wbase + (size_t)kc * 9216 + 512);
                    ca0 = __builtin_amdgcn_mfma_f32_16x16x32_bf16(af, b0, ca0, 0, 0, 0);
                    ca1 = __builtin_amdgcn_mfma_f32_16x16x32_bf16(af, b1, ca1, 0, 0, 0);
                }
            }
        } else {
#pragma unroll
            for (int tap = 0; tap < 9; ++tap) {
                int ky = tap / 3, kx = tap % 3;
                int r  = cho + ky - 1;
                int cx = cwo + kx - 1;
                bool v = (r >= 0) && (r < HH) && (cx >= 0) && (cx < WW);
                int hw = v ? (r * WW + cx) : 0;
                const __hip_bfloat16* abase = csrc + (size_t)hw * 256
                                              + quad * 8 + cks * 64;
                const __hip_bfloat16* wbase = cwg + (size_t)tap * 1024 + lane * 8;
#pragma unroll
                for (int kc = 0; kc < 2; ++kc) {
                    shortx8 af = *(const shortx8*)(abase + kc * 32);
                    if (!v) {
                        shortx8 zf = {0,0,0,0,0,0,0,0};
                        af = zf;
                    }
                    shortx8 b0 = *(const shortx8*)(wbase + (size_t)kc * 9216);
                    ca0 = __builtin_amdgcn_mfma_f32_16x16x32_bf16(af, b0, ca0, 0, 0, 0);
                }
            }
        }

        // partials -> s_red scratch (= Bs[1], 16x64x8 floats = 32 KB exactly)
        float* s_red = (float*)&Bs[1][0];
        *(floatx4*)&s_red[((size_t)w * 64 + lane) * 8]     = ca0;
        *(floatx4*)&s_red[((size_t)w * 64 + lane) * 8 + 4] = ca1;
    }
    __syncthreads();                // partials visible

    // ---- conv reduce + bias/sigmoid -> s_off / s_msk (R11 pattern) ----
    {
        int cg = w >> 3;
        int wr = w & 7;
        if (wr < 2) {               // wr == ph; 4 waves total (2 per g)
            float* s_red = (float*)&Bs[1][0];
            floatx4 a0, a1;
#pragma unroll
            for (int j = 0; j < 4; ++j) {
                int base = cg * 8 + wr;
                a0[j] = s_red[(((size_t)base     * 64 + lane)) * 8 + j]
                      + s_red[(((size_t)(base+2) * 64 + lane)) * 8 + j]
                      + s_red[(((size_t)(base+4) * 64 + lane)) * 8 + j]
                      + s_red[(((size_t)(base+6) * 64 + lane)) * 8 + j];
                a1[j] = s_red[(((size_t)base     * 64 + lane)) * 8 + 4 + j]
                      + s_red[(((size_t)(base+2) * 64 + lane)) * 8 + 4 + j]
                      + s_red[(((size_t)(base+4) * 64 + lane)) * 8 + 4 + j]
                      + s_red[(((size_t)(base+6) * 64 + lane)) * 8 + 4 + j];
            }
#pragma unroll
            for (int nf = 0; nf < 2; ++nf) {
                floatx4 a = nf ? a1 : a0;
                int n = nf * 16 + ln;
#pragma unroll
                for (int i2 = 0; i2 < 4; ++i2) {
                    int p = wr * 16 + quad * 4 + i2;   // pixel within tile
                    if (cg == 0) {
                        if (n < 18)
                            s_off[p][n] = a[i2] + off_b[n];
                    } else {
                        if (n < 9) {
                            float z = a[i2] + mod_b[n];
                            s_msk[p][n] = 2.f / (1.f + __expf(-z));
                        }
                    }
                }
            }
        }
    }
    __syncthreads();                // s_off/s_msk visible

    // ---- meta prologue: corner idx/weights for 32 pixels x 9 taps (LDS) ----
    for (int u = t; u < 32 * K2; u += 1024) {
        int pl_ = u / K2;
        int k  = u - pl_ * K2;
        int hw = (mt & 127) * 32 + pl_;
        int ho = hw >> 6, wo = hw & 63;
        float dy = s_off[pl_][2 * k];
        float dx = s_off[pl_][2 * k + 1];
        float m  = s_msk[pl_][k];
        float py = (float)(ho - 1 + k / 3) + dy;
        float px = (float)(wo - 1 + k % 3) + dx;
        float y0f = floorf(py), x0f = floorf(px);
        float wy1 = py - y0f, wx1 = px - x0f;
        float wy0 = 1.f - wy1, wx0 = 1.f - wx1;
        int y0 = (int)y0f, x0 = (int)x0f;
#pragma unroll
        for (int j = 0; j < 4; ++j) {
            int yy = y0 + (j >> 1);
            int xx = x0 + (j & 1);
            float wj = ((j == 0) ? wy0 * wx0 :
                        (j == 1) ? wy0 * wx1 :
                        (j == 2) ? wy1 * wx0 : wy1 * wx1) * m;
            bool valid = (yy >= 0) && (yy < HH) && (xx >= 0) && (xx < WW);
            s_mi[pl_][k][j] = valid ? (yy * WW + xx) : 0;
            s_mw[pl_][k][j] = valid ? wj : 0.f;
        }
    }

    int pl  = (t >> 3) & 31;        // gather pixel (0..31), threads 0..255
    int ch8 = t & 7;                // 8-channel group within 64
    bool gth = (t < 256);           // gather workers = waves 0..3 (uniform)
    int aslot = pl * 64 + ((ch8 ^ (pl & 7)) * 8);   // swizzled As column

    // per-tap meta (for the step currently being LOADED)
    int   mi0, mi1, mi2, mi3;
    float mw0, mw1, mw2, mw3;
    auto meta_load = [&](int k) {
        mi0 = s_mi[pl][k][0]; mi1 = s_mi[pl][k][1];
        mi2 = s_mi[pl][k][2]; mi3 = s_mi[pl][k][3];
        mw0 = s_mw[pl][k][0]; mw1 = s_mw[pl][k][1];
        mw2 = s_mw[pl][k][2]; mw3 = s_mw[pl][k][3];
    };

    // in-flight gather state: loaded corners + their weights (snapshot)
    shortx8 gc0, gc1, gc2, gc3;
    float   gw0, gw1, gw2, gw3;
    auto gather_load = [&](int cb) {
        const __hip_bfloat16* xr = xb + cb * 64 + ch8 * 8;
        gc0 = *(const shortx8*)(xr + (size_t)mi0 * 256);
        gc1 = *(const shortx8*)(xr + (size_t)mi1 * 256);
        gc2 = *(const shortx8*)(xr + (size_t)mi2 * 256);
        gc3 = *(const shortx8*)(xr + (size_t)mi3 * 256);
        gw0 = mw0; gw1 = mw1; gw2 = mw2; gw3 = mw3;
    };
    auto gather_store = [&](int buf) {
        shortx8 o;
#pragma unroll
        for (int j = 0; j < 8; ++j)
            o[j] = f2bf(gw0 * bf2f(gc0[j]) + gw1 * bf2f(gc1[j])
                      + gw2 * bf2f(gc2[j]) + gw3 * bf2f(gc3[j]));
        *(shortx8*)&As[buf][aslot] = o;
    };

    __syncthreads();                // meta visible
    if (gth) {
        meta_load(0);
        gather_load(0);             // corners for step 0
        gather_store(0);            // exposed once (prologue only)
        gather_load(1);             // corners for step 1 (cb=1, tap 0)
    }

    int swz = ln & 7;               // read-slot XOR key

    // ==================== main loop (verbatim R22, validated) ==============
    for (int kt = 0; kt < 36; ++kt) {
        int cur = kt & 1;
        int nxt = cur ^ 1;
        __syncthreads();            // buf[cur] staged; ALSO drains gc loads
        if (kt + 1 < 36) {
            int ko = (kt + 1) * 64;
#pragma unroll
            for (int h = 0; h < 2; ++h)
                gll16(gB + (size_t)(h * 8) * CK + ko, &Bs[nxt][w * 1024 + h * 512]);
        }
#pragma unroll
        for (int kh = 0; kh < 2; ++kh) {
            int slot = ((kh * 4 + quad) ^ swz) * 8;
            shortx8 af = *(const shortx8*)
                &As[cur][(wm * 16 + ln) * 64 + slot];
            shortx8 bf[2];
#pragma unroll
            for (int nf = 0; nf < 2; ++nf)
                bf[nf] = *(const shortx8*)
                    &Bs[cur][(wN * 32 + nf * 16 + ln) * 64 + slot];
#pragma unroll
            for (int nf = 0; nf < 2; ++nf)
                acc[nf] = __builtin_amdgcn_mfma_f32_16x16x32_bf16(
                    af, bf[nf], acc[nf], 0, 0, 0);
        }
        if (gth && kt + 1 < 36) gather_store(nxt);   // drained -> zero-wait
        if (gth && kt + 2 < 36) {                    // issue loads for kt+2
            int k2 = kt + 2;
            if ((k2 & 3) == 0) meta_load(k2 >> 2);
            gather_load(k2 & 3);
        }
    }

    // epilogue (R13-validated pattern): per-wave LDS transpose
    int bb = mt >> 7;
    int hw0 = (mt & 127) * 32 + wm * 16;
    float* sw = &s_out[w][0];
    int co_l = lane >> 2;
    int seg  = lane & 3;
#pragma unroll
    for (int nf = 0; nf < 2; ++nf) {
        *(floatx4*)&sw[ln * 20 + quad * 4] = acc[nf];
        floatx4 v0 = *(const floatx4*)&sw[co_l * 20 + seg * 4];
        int co = wN * 32 + nf * 16 + co_l;
        float* orow = out + ((size_t)(bb * COo + co) << 12) + hw0;
        *(floatx4*)&orow[seg * 4] = v0;
    }
}

// ---------------------------------------------------------------------------
extern "C" void kernel_launch(void* const* d_in, const int* in_sizes, int n_in,
                              void* d_out, int out_size, void* d_ws, size_t ws_size,
                              hipStream_t stream)
{
    const float* x     = (const float*)d_in[0];
    const float* resid = (const float*)d_in[1];
    const float* off_w = (const float*)d_in[2];
    const float* off_b = (const float*)d_in[3];
    const float* mod_w = (const float*)d_in[4];
    const float* mod_b = (const float*)d_in[5];
    const float* reg_w = (const float*)d_in[6];
    float* out = (float*)d_out;

    float* ws = (float*)d_ws;
    __hip_bfloat16* Wbf  = (__hip_bfloat16*)(ws + O_WBF);
    __hip_bfloat16* Wpk  = (__hip_bfloat16*)(ws + O_WPK);
    __hip_bfloat16* xT   = (__hip_bfloat16*)(ws + O_XT);
    __hip_bfloat16* resT = (__hip_bfloat16*)(ws + O_RT);

    // fused transpose (2048 blocks) + weight pack (2304 blocks)
    prep_kernel<<<2048 + (CK * COo + 255) / 256, 256, 0, stream>>>(
        x, resid, reg_w, off_w, mod_w, xT, resT, Wbf, Wpk);

    mega_kernel<<<256, 1024, 0, stream>>>(xT, resT, Wpk, off_b, mod_b, Wbf, out);
}